// Round 1
// baseline (2106.050 us; speedup 1.0000x reference)
//
#include <hip/hip_runtime.h>

// CustomRNN: B=128, T=64, D=H=256, L=2, 3-node cell.
// Round 6: N-SPLIT x2. Round 5 was L1-consumer per-CU weight-ingest bound
// (33.5 MB/CU at ~23 B/cyc => 615us). Split every matmul's output dim across
// a WG pair: 32 WGs (16 L0 + 16 L1), each owns 128 of 256 output cols =>
// per-CU weight stream halves (L1 16.8 MB, L0 12.6 MB). Node values are
// half-exchanged between pair members via fresh-per-t global slots + magic
// flags; own-K phase runs from LDS while the partner half transits global.
// Also: Win0 transposed to f16 and xw_kernel rewritten with vector B-loads.

typedef _Float16 f16;
typedef __attribute__((ext_vector_type(8))) _Float16 f16x8;
typedef __attribute__((ext_vector_type(4))) float f32x4;
typedef __attribute__((ext_vector_type(4))) float float4v;

#define Tt 64
#define FLAG_MAGIC 0x52570000

// ---- workspace byte offsets ----
// Wh0T  f16 25,165,824 | Win1T f16 8,388,608 | Wh1T f16 25,165,824
// Win0T f16  8,388,608 | xw   f32 8,388,608 | hseq f16 4,194,304
// nx (n0/n1 halves) 16,777,216 | h1x 4,194,304 | flags 24,576  => ~96 MiB
#define WS_WH0T   0
#define WS_WIN1T  25165824
#define WS_WH1T   33554432
#define WS_WIN0T  58720256
#define WS_XW     67108864
#define WS_HSEQ   75497472
#define WS_NX     79691776
#define WS_H1X    96468992
#define WS_FLAGS  100663296

// ---------------- helpers ----------------
__device__ __forceinline__ void sb() { __builtin_amdgcn_sched_barrier(0); }

template <int N>
__device__ __forceinline__ void waitvm() {
  // s_waitcnt vmcnt(N), lgkm=15 (no wait), exp=7 (no wait); gfx9 encoding
  __builtin_amdgcn_s_waitcnt(0x0F70 | (N & 15) | ((N >> 4) << 14));
}
__device__ __forceinline__ void waitlgkm0() { __builtin_amdgcn_s_waitcnt(0xC07F); }

__device__ __forceinline__ void barx() {
  asm volatile("s_waitcnt lgkmcnt(0)\n\ts_barrier" ::: "memory");
}

__device__ __forceinline__ void dma16(const void* g, void* l) {
  __builtin_amdgcn_global_load_lds(
      (const __attribute__((address_space(1))) unsigned int*)g,
      (__attribute__((address_space(3))) unsigned int*)l, 16, 0, 0);
}

__device__ __forceinline__ float tanh_fast(float x) {
  float xc = fminf(fmaxf(x, -15.f), 15.f);
  float e = __expf(2.f * xc);
  return (e - 1.f) / (e + 1.f);
}
__device__ __forceinline__ float sigmoid_fast(float x) { return 1.f / (1.f + __expf(-x)); }

// 4x dma16 = one 16-row x 128-col (256B) K-half slice of a wave's n-slice.
__device__ __forceinline__ void dmaHalf(const char* gsrc, char* ldst, const int (&off)[4]) {
#pragma unroll
  for (int d = 0; d < 4; ++d) dma16(gsrc + off[d], ldst + d * 1024);
}
__device__ __forceinline__ void loadB(f16x8 (&b)[4], const char* wb, const int (&bo)[4]) {
#pragma unroll
  for (int kt = 0; kt < 4; ++kt) b[kt] = *(const f16x8*)(wb + bo[kt]);
}
__device__ __forceinline__ void loadA_lds(f16x8 (&a)[4], const char* aP, int q) {
#pragma unroll
  for (int kt = 0; kt < 4; ++kt) a[kt] = *(const f16x8*)(aP + kt * 64 + q * 16);
}
// A-fragments straight from a global f16 [16][stride/2] tile (K-half = 128)
__device__ __forceinline__ void loadA_g(f16x8 (&a)[4], const char* gp, int stride, int q, int mn) {
#pragma unroll
  for (int kt = 0; kt < 4; ++kt)
    a[kt] = *(const f16x8*)(gp + mn * stride + kt * 64 + q * 16);
}
// A-fragments from a global f32 [16][256] tile (t=0 hidden), one K-half
__device__ __forceinline__ void loadA_f32(f16x8 (&a)[4], const float* hp, int colbase, int q, int mn) {
#pragma unroll
  for (int kt = 0; kt < 4; ++kt) {
    const float4v* p = (const float4v*)(hp + mn * 256 + colbase + kt * 32 + q * 8);
    float4v x0 = p[0], x1 = p[1];
    f16x8 v;
    v[0] = (f16)x0.x; v[1] = (f16)x0.y; v[2] = (f16)x0.z; v[3] = (f16)x0.w;
    v[4] = (f16)x1.x; v[5] = (f16)x1.y; v[6] = (f16)x1.z; v[7] = (f16)x1.w;
    a[kt] = v;
  }
}
__device__ __forceinline__ void mfma4(f32x4& acc, const f16x8 (&a)[4], const f16x8 (&b)[4]) {
#pragma unroll
  for (int kt = 0; kt < 4; ++kt)
    acc = __builtin_amdgcn_mfma_f32_16x16x32_f16(a[kt], b[kt], acc, 0, 0, 0);
}

// exchange slot/flag indexing
__device__ __forceinline__ size_t nx_off(int l, int g, int t, int node, int nh) {
  return (size_t)((((l * 8 + g) * 64 + t) * 2 + node) * 2 + nh) * 4096;
}
__device__ __forceinline__ int fnidx(int l, int g, int t, int node, int nh) {
  return 1024 + ((((l * 8 + g) * 64 + t) * 2 + node) * 2 + nh);
}

// release-publish: drain own vmem, agent fence, WG barrier, tagged flag store
__device__ __forceinline__ void publish(int* f, int tag) {
  waitvm<0>();
  __threadfence();
  __syncthreads();
  if (threadIdx.x == 0)
    __hip_atomic_store(f, tag, __ATOMIC_RELEASE, __HIP_MEMORY_SCOPE_AGENT);
}
__device__ __forceinline__ void acquire(const int* f, int tag) {
  while (__hip_atomic_load(f, __ATOMIC_ACQUIRE, __HIP_MEMORY_SCOPE_AGENT) != tag) {}
}

// ---------------- transpose+convert: [k][n] f32 -> [n][k] f16 ----------------
// 512 matrices: 192 Wh0 + 64 Win1 + 192 Wh1 + 64 Win0
__global__ __launch_bounds__(256) void transpose_cvt_kernel(
    const float* __restrict__ Wh0, const float* __restrict__ Win1,
    const float* __restrict__ Wh1, const float* __restrict__ Win0,
    f16* __restrict__ Wh0T, f16* __restrict__ Win1T, f16* __restrict__ Wh1T,
    f16* __restrict__ Win0T) {
  __shared__ float tile[256 * 33];
  const int bid = blockIdx.x;
  const int mat = bid >> 3, n0 = (bid & 7) << 5;
  const float* src; f16* dst;
  if (mat < 192)      { src = Wh0  + (size_t)mat * 65536;         dst = Wh0T  + (size_t)mat * 65536; }
  else if (mat < 256) { src = Win1 + (size_t)(mat - 192) * 65536; dst = Win1T + (size_t)(mat - 192) * 65536; }
  else if (mat < 448) { src = Wh1  + (size_t)(mat - 256) * 65536; dst = Wh1T  + (size_t)(mat - 256) * 65536; }
  else                { src = Win0 + (size_t)(mat - 448) * 65536; dst = Win0T + (size_t)(mat - 448) * 65536; }
  const int tid = threadIdx.x;
  const int c2 = tid & 15, kl = tid >> 4;
#pragma unroll
  for (int p = 0; p < 16; ++p) {
    const int k = kl + p * 16;
    float2 v = *(const float2*)(src + k * 256 + n0 + c2 * 2);
    tile[k * 33 + c2 * 2]     = v.x;
    tile[k * 33 + c2 * 2 + 1] = v.y;
  }
  __syncthreads();
  const int n = tid & 7, c = tid >> 3;
#pragma unroll
  for (int it = 0; it < 4; ++it) {
    const int nn = n + it * 8;
    f16x8 vv;
#pragma unroll
    for (int i = 0; i < 8; ++i) vv[i] = (f16)tile[(c * 8 + i) * 33 + nn];
    *(f16x8*)((char*)dst + (size_t)(n0 + nn) * 512 + c * 16) = vv;
  }
}

// ---------------- xw precompute: xw[t,b,h] = x[b,t,:]@Win0[t] + b0[t,0,h] ----
// B-fragments as 16B vector loads from Win0T ([n][k] f16) -- L2-shared across
// the 8 batch-tile WGs per t. Replaces the old 4B-strided raw-f32 reads.
__global__ __launch_bounds__(512, 2) void xw_kernel(
    const float* __restrict__ x, const f16* __restrict__ Win0T,
    const float* __restrict__ b0, float* __restrict__ xw) {
  const int t = blockIdx.x >> 3, bb = blockIdx.x & 7;
  const int rb = bb << 4;
  const int tid = threadIdx.x, lane = tid & 63, w = tid >> 6;
  const int q = lane >> 4, mn = lane & 15, dr = q * 4;
  const f16* wt = Win0T + (size_t)t * 65536;
  const float4v* xr = (const float4v*)(x + ((size_t)(rb + mn) * Tt + t) * 256);
  f32x4 acc[2] = {{0.f,0.f,0.f,0.f},{0.f,0.f,0.f,0.f}};
#pragma unroll
  for (int kt = 0; kt < 8; ++kt) {
    const int k0 = kt * 32 + q * 8;
    float4v x0 = xr[k0 / 4], x1 = xr[k0 / 4 + 1];
    f16x8 a = {(f16)x0.x, (f16)x0.y, (f16)x0.z, (f16)x0.w,
               (f16)x1.x, (f16)x1.y, (f16)x1.z, (f16)x1.w};
#pragma unroll
    for (int nt = 0; nt < 2; ++nt) {
      f16x8 b = *(const f16x8*)(wt + (size_t)(w * 32 + nt * 16 + mn) * 256 + k0);
      acc[nt] = __builtin_amdgcn_mfma_f32_16x16x32_f16(a, b, acc[nt], 0, 0, 0);
    }
  }
#pragma unroll
  for (int nt = 0; nt < 2; ++nt) {
    const int n = w * 32 + nt * 16 + mn;
    const float bv = b0[(size_t)t * 768 + n];
#pragma unroll
    for (int r = 0; r < 4; ++r)
      xw[(size_t)t * 32768 + (size_t)(rb + dr + r) * 256 + n] = acc[nt][r] + bv;
  }
}

// ---------------- recurrent kernel: 32 WGs (16 L0 + 16 L1) ------------------
// WG (layer, g, nh): 16 batch rows (rb=g*16), output cols [nh*128, nh*128+128).
// 8 waves x 16 cols. Per matmul: phase over own K-half (A from LDS) + phase
// over partner K-half (A-fragments from the partner's published global slot).
__global__ __launch_bounds__(512, 1) void rnn_kernel(
    const float* __restrict__ hidden,
    const f16* __restrict__ Wh0T, const float* __restrict__ b0,
    const f16* __restrict__ Win1T, const f16* __restrict__ Wh1T,
    const float* __restrict__ b1, const float* __restrict__ xw,
    char* __restrict__ hseqb, char* __restrict__ nxb, char* __restrict__ h1xb,
    int* __restrict__ flags, float* __restrict__ out) {
  // 96 KB requested (74,240 used) so at most ONE WG per CU -> full per-CU BW
  __shared__ __align__(16) char smem[98304];
  char* wlds = smem;            // 8 waves x 8 KB (bufA 4K + bufB 4K)
  char* abuf = smem + 65536;    // recurrent h, own half: [16][272B]
  char* nbuf = smem + 69888;    // node value, own half: [16][272B]

  const int tid = threadIdx.x;
  const int lane = tid & 63, w = tid >> 6;
  const int q = lane >> 4, mn = lane & 15;
  const bool isL0 = blockIdx.x < 16;
  const int g = (blockIdx.x >> 1) & 7;
  const int nh = blockIdx.x & 1, ph = nh ^ 1;
  const int rb = g << 4, dr = q * 4;
  const int nc = nh * 128 + w * 16 + mn;          // global output col
  const int wwb = nh * 65536 + w * 8192;          // wave's n-slice byte base

  char* bufA = wlds + w * 8192;
  char* bufB = bufA + 4096;

  int off[4], bo[4];
#pragma unroll
  for (int d = 0; d < 4; ++d) {
    const int row = 4 * d + q;
    off[d] = row * 512 + ((mn ^ row) << 4);       // XOR-swizzled global src
  }
#pragma unroll
  for (int kt = 0; kt < 4; ++kt)
    bo[kt] = mn * 256 + (((kt * 4 + q) ^ mn) << 4);

  // init recurrent state: own half of hidden
  const float* hsrc = hidden + (isL0 ? 0 : 32768) + (size_t)rb * 256;
  for (int i = tid; i < 2048; i += 512) {
    const int m = i >> 7, kl = i & 127;
    *(f16*)(abuf + m * 272 + kl * 2) = (f16)hsrc[m * 256 + nh * 128 + kl];
  }

  const f32x4 zero4 = {0.f, 0.f, 0.f, 0.f};

  if (isL0) {
    // =================== LAYER-0 ===================
    const char* WB = (const char*)Wh0T;           // [t][3][256n][256k] f16
    { const char* w0 = WB + wwb;                  // prelude: m0(t=0) halves
      dmaHalf(w0 + nh * 256, bufA, off);
      dmaHalf(w0 + ph * 256, bufB, off); }
    barx();

#pragma unroll 1
    for (int t = 0; t < Tt; ++t) {
      const bool last = (t == Tt - 1);
      const char* wt = WB + (size_t)t * 393216 + wwb;
      const int tag = FLAG_MAGIC | (t + 1);

      f16x8 a[4], b[4], af[4];
      f32x4 acc = zero4;
      // --- m0_own: h(own cols) @ Wh0[0][k=own]  [out: 8 -> wait to 4] ---
      waitvm<4>(); sb();
      loadA_lds(a, abuf + mn * 272, q);
      loadB(b, bufA, bo);
      waitlgkm0(); sb();
      mfma4(acc, a, b);
      sb();
      // --- poll partner h0'(t-1) (drains vm) ---
      if (t > 0) acquire(&flags[(g * 64 + t - 1) * 2 + ph], FLAG_MAGIC | t);
      sb();
      // --- per-t loads + dma m1_own->bufA ---
      float xwv[4];
#pragma unroll
      for (int r = 0; r < 4; ++r)
        xwv[r] = xw[(size_t)t * 32768 + (size_t)(rb + dr + r) * 256 + nc];
      const float bv1 = b0[(size_t)t * 768 + 256 + nc];
      const float bv2 = b0[(size_t)t * 768 + 512 + nc];
      if (t > 0) loadA_g(af, hseqb + (size_t)(g * 64 + t - 1) * 8192 + ph * 256, 512, q, mn);
      else       loadA_f32(af, hsrc, ph * 128, q, mn);
      dmaHalf(wt + 131072 + nh * 256, bufA, off);
      sb();
      // --- m0_part: partner h half @ Wh0[0][k=part]
      //     vm ledger: t=0: prelB(4 old) + 18 new -> wait<18>; t>0 no-op ---
      waitvm<18>(); sb();
      loadB(b, bufB, bo);
      waitlgkm0(); sb();
      mfma4(acc, af, b);
      sb();
      // --- epi0: n0 = tanh(acc + xw) ; publish own half ---
      float n0v[4];
#pragma unroll
      for (int r = 0; r < 4; ++r) {
        float v = tanh_fast(acc[r] + xwv[r]);
        n0v[r] = v;
        *(f16*)(nbuf + (dr + r) * 272 + (w * 16 + mn) * 2) = (f16)v;
      }
      { char* slot = nxb + nx_off(0, g, t, 0, nh);
#pragma unroll
        for (int r = 0; r < 4; ++r)
          *(f16*)(slot + (dr + r) * 256 + (w * 16 + mn) * 2) = (f16)n0v[r]; }
      publish(&flags[fnidx(0, g, t, 0, nh)], tag);
      // --- m1_own + dma m1_part->bufB ---
      acc = zero4;
      loadA_lds(a, nbuf + mn * 272, q);
      loadB(b, bufA, bo);
      waitlgkm0(); sb();
      dmaHalf(wt + 131072 + ph * 256, bufB, off);
      sb();
      mfma4(acc, a, b);
      sb();
      // --- poll partner n0; af; dma m2_own->bufA ---
      acquire(&flags[fnidx(0, g, t, 0, ph)], tag);
      sb();
      loadA_g(af, nxb + nx_off(0, g, t, 0, ph), 256, q, mn);
      dmaHalf(wt + 262144 + nh * 256, bufA, off);
      sb();
      // --- m1_part ---
      loadB(b, bufB, bo);
      waitlgkm0(); sb();
      mfma4(acc, af, b);
      sb();
      // --- epi1: n1 = relu(acc+b1)+n0 ---
      float n1v[4];
#pragma unroll
      for (int r = 0; r < 4; ++r) n1v[r] = fmaxf(acc[r] + bv1, 0.f) + n0v[r];
      barx();  // WAR: all waves done reading nbuf(n0) in m1_own
#pragma unroll
      for (int r = 0; r < 4; ++r)
        *(f16*)(nbuf + (dr + r) * 272 + (w * 16 + mn) * 2) = (f16)n1v[r];
      { char* slot = nxb + nx_off(0, g, t, 1, nh);
#pragma unroll
        for (int r = 0; r < 4; ++r)
          *(f16*)(slot + (dr + r) * 256 + (w * 16 + mn) * 2) = (f16)n1v[r]; }
      publish(&flags[fnidx(0, g, t, 1, nh)], tag);
      // --- m2_own + dma m2_part->bufB ---
      acc = zero4;
      loadA_lds(a, nbuf + mn * 272, q);
      loadB(b, bufA, bo);
      waitlgkm0(); sb();
      dmaHalf(wt + 262144 + ph * 256, bufB, off);
      sb();
      mfma4(acc, a, b);
      sb();
      // --- poll partner n1; af ---
      acquire(&flags[fnidx(0, g, t, 1, ph)], tag);
      sb();
      loadA_g(af, nxb + nx_off(0, g, t, 1, ph), 256, q, mn);
      sb();
      // --- m2_part ---
      loadB(b, bufB, bo);
      waitlgkm0(); sb();
      mfma4(acc, af, b);
      sb();
      // --- epi2: h0' = 0.5(n1 + sigmoid(acc+b2) + n0); publish to hseq ---
#pragma unroll
      for (int r = 0; r < 4; ++r) {
        float s = sigmoid_fast(acc[r] + bv2);
        float hv = 0.5f * (n1v[r] + s + n0v[r]);
        f16 h16 = (f16)hv;
        *(f16*)(abuf + (dr + r) * 272 + (w * 16 + mn) * 2) = h16;
        *(f16*)(hseqb + (size_t)(g * 64 + t) * 8192 + (dr + r) * 512 + nc * 2) = h16;
        if (last) out[2097152 + (size_t)(rb + dr + r) * 256 + nc] = hv;
      }
      publish(&flags[(g * 64 + t) * 2 + nh], tag);
      if (!last) {  // dma next-t m0 halves
        const char* wn = WB + (size_t)(t + 1) * 393216 + wwb;
        dmaHalf(wn + nh * 256, bufA, off);
        dmaHalf(wn + ph * 256, bufB, off);
      }
    }
  } else {
    // =================== LAYER-1 ===================
    const char* WI = (const char*)Win1T;          // [t][256n][256k]
    const char* WH = (const char*)Wh1T;           // [t][3][256n][256k]
    { const char* w0 = WH + wwb;                  // prelude: m4(t=0) halves
      dmaHalf(w0 + nh * 256, bufA, off);
      dmaHalf(w0 + ph * 256, bufB, off); }
    barx();

#pragma unroll 1
    for (int t = 0; t < Tt; ++t) {
      const bool last = (t == Tt - 1);
      const char* wht = WH + (size_t)t * 393216 + wwb;
      const char* wit = WI + (size_t)t * 131072 + wwb;
      const int tag = FLAG_MAGIC | (t + 1);

      f16x8 a[4], b[4], af[4], ah[4];
      f32x4 acc = zero4;
      // --- m4_own: h1(own) @ Wh1[0][k=own] ---
      waitvm<4>(); sb();
      loadA_lds(a, abuf + mn * 272, q);
      loadB(b, bufA, bo);
      waitlgkm0(); sb();
      mfma4(acc, a, b);
      sb();
      // --- poll partner h1'(t-1) ---
      if (t > 0) acquire(&flags[5120 + (g * 64 + t - 1) * 2 + ph], FLAG_MAGIC | t);
      sb();
      // --- biases, af_h1, dma m3(k-lo)->bufA ---
      const float bv0 = b1[(size_t)t * 768 + nc];
      const float bv1 = b1[(size_t)t * 768 + 256 + nc];
      const float bv2 = b1[(size_t)t * 768 + 512 + nc];
      if (t > 0) loadA_g(af, h1xb + (size_t)((g * 64 + t - 1) * 2 + ph) * 4096, 256, q, mn);
      else       loadA_f32(af, hsrc, ph * 128, q, mn);
      dmaHalf(wit + 0, bufA, off);
      sb();
      // --- m4_part  [t=0: prelB(4 old) + 15 new -> wait<15>] ---
      waitvm<15>(); sb();
      loadB(b, bufB, bo);
      waitlgkm0(); sb();
      mfma4(acc, af, b);
      sb();
      // --- wait h0'(t): both L0 halves (paired 64-bit flag read) ---
      { const unsigned long long want2 =
            ((unsigned long long)(unsigned)tag << 32) | (unsigned)tag;
        const unsigned long long* fp = (const unsigned long long*)&flags[(g * 64 + t) * 2];
        while (__hip_atomic_load(fp, __ATOMIC_ACQUIRE, __HIP_MEMORY_SCOPE_AGENT) != want2) {} }
      sb();
      // --- dma m3(k-hi)->bufB; h0' A-fragments (full K) ---
      dmaHalf(wit + 256, bufB, off);
      loadA_g(af, hseqb + (size_t)(g * 64 + t) * 8192, 512, q, mn);        // k 0:127
      loadA_g(ah, hseqb + (size_t)(g * 64 + t) * 8192 + 256, 512, q, mn);  // k 128:255
      sb();
      // --- m3_p0 (bufA) + dma m5_own->bufA ---
      loadB(b, bufA, bo);
      waitlgkm0(); sb();
      dmaHalf(wht + 131072 + nh * 256, bufA, off);
      sb();
      mfma4(acc, af, b);
      sb();
      // --- m3_p1 (bufB) + dma m5_part->bufB  [m3hi oldest of 16 -> wait<12>] ---
      waitvm<12>(); sb();
      loadB(b, bufB, bo);
      waitlgkm0(); sb();
      dmaHalf(wht + 131072 + ph * 256, bufB, off);
      sb();
      mfma4(acc, ah, b);
      sb();
      // --- epi0': n0' = tanh(m4+m3+b0) ---
      float n0v[4];
#pragma unroll
      for (int r = 0; r < 4; ++r) {
        float v = tanh_fast(acc[r] + bv0);
        n0v[r] = v;
        *(f16*)(nbuf + (dr + r) * 272 + (w * 16 + mn) * 2) = (f16)v;
      }
      { char* slot = nxb + nx_off(1, g, t, 0, nh);
#pragma unroll
        for (int r = 0; r < 4; ++r)
          *(f16*)(slot + (dr + r) * 256 + (w * 16 + mn) * 2) = (f16)n0v[r]; }
      publish(&flags[fnidx(1, g, t, 0, nh)], tag);
      // --- m5_own + dma m6_own->bufA ---
      acc = zero4;
      loadA_lds(a, nbuf + mn * 272, q);
      loadB(b, bufA, bo);
      waitlgkm0(); sb();
      dmaHalf(wht + 262144 + nh * 256, bufA, off);
      sb();
      mfma4(acc, a, b);
      sb();
      // --- poll partner n0'; af ---
      acquire(&flags[fnidx(1, g, t, 0, ph)], tag);
      sb();
      loadA_g(af, nxb + nx_off(1, g, t, 0, ph), 256, q, mn);
      sb();
      // --- m5_part + dma m6_part->bufB ---
      loadB(b, bufB, bo);
      waitlgkm0(); sb();
      dmaHalf(wht + 262144 + ph * 256, bufB, off);
      sb();
      mfma4(acc, af, b);
      sb();
      // --- epi1': n1' ---
      float n1v[4];
#pragma unroll
      for (int r = 0; r < 4; ++r) n1v[r] = fmaxf(acc[r] + bv1, 0.f) + n0v[r];
      barx();  // WAR: nbuf(n0') reads done in m5_own
#pragma unroll
      for (int r = 0; r < 4; ++r)
        *(f16*)(nbuf + (dr + r) * 272 + (w * 16 + mn) * 2) = (f16)n1v[r];
      { char* slot = nxb + nx_off(1, g, t, 1, nh);
#pragma unroll
        for (int r = 0; r < 4; ++r)
          *(f16*)(slot + (dr + r) * 256 + (w * 16 + mn) * 2) = (f16)n1v[r]; }
      publish(&flags[fnidx(1, g, t, 1, nh)], tag);
      // --- m6_own ---
      acc = zero4;
      loadA_lds(a, nbuf + mn * 272, q);
      loadB(b, bufA, bo);
      waitlgkm0(); sb();
      mfma4(acc, a, b);
      sb();
      // --- poll partner n1'; af ---
      acquire(&flags[fnidx(1, g, t, 1, ph)], tag);
      sb();
      loadA_g(af, nxb + nx_off(1, g, t, 1, ph), 256, q, mn);
      sb();
      // --- m6_part ---
      loadB(b, bufB, bo);
      waitlgkm0(); sb();
      mfma4(acc, af, b);
      sb();
      // --- epi2': h1' = 0.5(n1' + sigmoid(acc+b2) + n0'); out + exchange ---
#pragma unroll
      for (int r = 0; r < 4; ++r) {
        float s = sigmoid_fast(acc[r] + bv2);
        float hv = 0.5f * (n1v[r] + s + n0v[r]);
        f16 h16 = (f16)hv;
        *(f16*)(abuf + (dr + r) * 272 + (w * 16 + mn) * 2) = h16;
        *(f16*)(h1xb + (size_t)((g * 64 + t) * 2 + nh) * 4096 +
                (dr + r) * 256 + (w * 16 + mn) * 2) = h16;
        out[((size_t)(rb + dr + r) * Tt + t) * 256 + nc] = hv;
        if (last) out[2097152 + 32768 + (size_t)(rb + dr + r) * 256 + nc] = hv;
      }
      publish(&flags[5120 + (g * 64 + t) * 2 + nh], tag);
      if (!last) {  // dma next-t m4 halves
        const char* wn = WH + (size_t)(t + 1) * 393216 + wwb;
        dmaHalf(wn + nh * 256, bufA, off);
        dmaHalf(wn + ph * 256, bufB, off);
      }
    }
  }
}

// ---------------- launch ----------------
extern "C" void kernel_launch(void* const* d_in, const int* in_sizes, int n_in,
                              void* d_out, int out_size, void* d_ws, size_t ws_size,
                              hipStream_t stream) {
  (void)in_sizes; (void)n_in; (void)out_size; (void)ws_size;
  const float* x      = (const float*)d_in[0];
  const float* hidden = (const float*)d_in[1];
  const float* Win0   = (const float*)d_in[2];
  const float* Wh0    = (const float*)d_in[3];
  const float* b0     = (const float*)d_in[4];
  const float* Win1   = (const float*)d_in[5];
  const float* Wh1    = (const float*)d_in[6];
  const float* b1     = (const float*)d_in[7];
  float* out = (float*)d_out;

  char* ws = (char*)d_ws;
  f16* Wh0T  = (f16*)(ws + WS_WH0T);
  f16* Win1T = (f16*)(ws + WS_WIN1T);
  f16* Wh1T  = (f16*)(ws + WS_WH1T);
  f16* Win0T = (f16*)(ws + WS_WIN0T);
  float* xwp = (float*)(ws + WS_XW);
  char* hseq = ws + WS_HSEQ;
  char* nx   = ws + WS_NX;
  char* h1x  = ws + WS_H1X;
  int* flags = (int*)(ws + WS_FLAGS);

  transpose_cvt_kernel<<<dim3(4096), dim3(256), 0, stream>>>(
      Wh0, Win1, Wh1, Win0, Wh0T, Win1T, Wh1T, Win0T);
  xw_kernel<<<dim3(512), dim3(512), 0, stream>>>(x, Win0T, b0, xwp);
  rnn_kernel<<<dim3(32), dim3(512), 0, stream>>>(
      hidden, Wh0T, b0, Win1T, Wh1T, b1, xwp, hseq, nx, h1x, flags, out);
}

// Round 2
// 854.684 us; speedup vs baseline: 2.4641x; 2.4641x over previous
//
#include <hip/hip_runtime.h>

// CustomRNN: B=128, T=64, D=H=256, L=2, 3-node cell.
// Round 7: revert to round-5 structure (N-split round 6 was sync-latency
// bound: 3 cross-CU round trips/t + waitvm<0> in publish killed the DMA
// pipeline => 1959us). Round-5 is per-CU weight-ingest bound (~23 B/cyc,
// consistent with ~16KB outstanding misses at ~700cy L3/HBM latency).
// Fix: XCD CO-LOCATION. All 8 L1 WGs stream identical weights; blockIdx%8
// = XCD (round-robin) so round 5 gave them 8 different L2s (FETCH=3.5x
// unique). Launch grid=32, map L0 WGs -> XCDs {0,1} (4 CUs each), L1 ->
// XCDs {4,5}; rest exit. Co-located WGs self-distribute misses and hit
// each other's L2 lines (no sync needed; laggard catches up via hits).
// Also kept from round 6 (verified correct): Win0T f16 transpose + vector
// xw_kernel.

typedef _Float16 f16;
typedef __attribute__((ext_vector_type(8))) _Float16 f16x8;
typedef __attribute__((ext_vector_type(4))) float f32x4;
typedef __attribute__((ext_vector_type(4))) float float4v;

#define Tt 64
#define FLAG_MAGIC 0x52570000

// ---- workspace byte offsets ----
// Wh0T f16 25,165,824 | Win1T f16 8,388,608 | Wh1T f16 25,165,824
// Win0T f16 8,388,608 | xw f32 8,388,608 | hseq f16 4,194,304 | flags 2,048
#define WS_WH0T   0
#define WS_WIN1T  25165824
#define WS_WH1T   33554432
#define WS_WIN0T  58720256
#define WS_XW     67108864
#define WS_HSEQ   75497472
#define WS_FLAGS  79691776

// ---------------- helpers ----------------
__device__ __forceinline__ void sb() { __builtin_amdgcn_sched_barrier(0); }

template <int N>
__device__ __forceinline__ void waitvm() {
  // s_waitcnt vmcnt(N), lgkm=15 (no wait), exp=7 (no wait); gfx9 encoding
  __builtin_amdgcn_s_waitcnt(0x0F70 | (N & 15) | ((N >> 4) << 14));
}
__device__ __forceinline__ void waitlgkm0() { __builtin_amdgcn_s_waitcnt(0xC07F); }

__device__ __forceinline__ void barx() {
  // barrier draining LDS ops only -- weight DMAs (vmcnt) stay in flight
  asm volatile("s_waitcnt lgkmcnt(0)\n\ts_barrier" ::: "memory");
}

__device__ __forceinline__ void dma16(const void* g, void* l) {
  __builtin_amdgcn_global_load_lds(
      (const __attribute__((address_space(1))) unsigned int*)g,
      (__attribute__((address_space(3))) unsigned int*)l, 16, 0, 0);
}

__device__ __forceinline__ float tanh_fast(float x) {
  float xc = fminf(fmaxf(x, -15.f), 15.f);
  float e = __expf(2.f * xc);
  return (e - 1.f) / (e + 1.f);
}
__device__ __forceinline__ float sigmoid_fast(float x) { return 1.f / (1.f + __expf(-x)); }

// ---------------- transpose+convert: [k][n] f32 -> [n][k] f16 ----------------
// 512 matrices: 192 Wh0 + 64 Win1 + 192 Wh1 + 64 Win0
__global__ __launch_bounds__(256) void transpose_cvt_kernel(
    const float* __restrict__ Wh0, const float* __restrict__ Win1,
    const float* __restrict__ Wh1, const float* __restrict__ Win0,
    f16* __restrict__ Wh0T, f16* __restrict__ Win1T, f16* __restrict__ Wh1T,
    f16* __restrict__ Win0T) {
  __shared__ float tile[256 * 33];
  const int bid = blockIdx.x;
  const int mat = bid >> 3, n0 = (bid & 7) << 5;
  const float* src; f16* dst;
  if (mat < 192)      { src = Wh0  + (size_t)mat * 65536;         dst = Wh0T  + (size_t)mat * 65536; }
  else if (mat < 256) { src = Win1 + (size_t)(mat - 192) * 65536; dst = Win1T + (size_t)(mat - 192) * 65536; }
  else if (mat < 448) { src = Wh1  + (size_t)(mat - 256) * 65536; dst = Wh1T  + (size_t)(mat - 256) * 65536; }
  else                { src = Win0 + (size_t)(mat - 448) * 65536; dst = Win0T + (size_t)(mat - 448) * 65536; }
  const int tid = threadIdx.x;
  const int c2 = tid & 15, kl = tid >> 4;
#pragma unroll
  for (int p = 0; p < 16; ++p) {
    const int k = kl + p * 16;
    float2 v = *(const float2*)(src + k * 256 + n0 + c2 * 2);
    tile[k * 33 + c2 * 2]     = v.x;
    tile[k * 33 + c2 * 2 + 1] = v.y;
  }
  __syncthreads();
  const int n = tid & 7, c = tid >> 3;
#pragma unroll
  for (int it = 0; it < 4; ++it) {
    const int nn = n + it * 8;
    f16x8 vv;
#pragma unroll
    for (int i = 0; i < 8; ++i) vv[i] = (f16)tile[(c * 8 + i) * 33 + nn];
    *(f16x8*)((char*)dst + (size_t)(n0 + nn) * 512 + c * 16) = vv;
  }
}

// ---------------- xw precompute: xw[t,b,h] = x[b,t,:]@Win0[t] + b0[t,0,h] ----
// B-fragments as 16B vector loads from Win0T ([n][k] f16) -- L2-shared across
// the 8 batch-tile WGs per t.
__global__ __launch_bounds__(512, 2) void xw_kernel(
    const float* __restrict__ x, const f16* __restrict__ Win0T,
    const float* __restrict__ b0, float* __restrict__ xw) {
  const int t = blockIdx.x >> 3, bb = blockIdx.x & 7;
  const int rb = bb << 4;
  const int tid = threadIdx.x, lane = tid & 63, w = tid >> 6;
  const int q = lane >> 4, mn = lane & 15, dr = q * 4;
  const f16* wt = Win0T + (size_t)t * 65536;
  const float4v* xr = (const float4v*)(x + ((size_t)(rb + mn) * Tt + t) * 256);
  f32x4 acc[2] = {{0.f,0.f,0.f,0.f},{0.f,0.f,0.f,0.f}};
#pragma unroll
  for (int kt = 0; kt < 8; ++kt) {
    const int k0 = kt * 32 + q * 8;
    float4v x0 = xr[k0 / 4], x1 = xr[k0 / 4 + 1];
    f16x8 a = {(f16)x0.x, (f16)x0.y, (f16)x0.z, (f16)x0.w,
               (f16)x1.x, (f16)x1.y, (f16)x1.z, (f16)x1.w};
#pragma unroll
    for (int nt = 0; nt < 2; ++nt) {
      f16x8 b = *(const f16x8*)(wt + (size_t)(w * 32 + nt * 16 + mn) * 256 + k0);
      acc[nt] = __builtin_amdgcn_mfma_f32_16x16x32_f16(a, b, acc[nt], 0, 0, 0);
    }
  }
#pragma unroll
  for (int nt = 0; nt < 2; ++nt) {
    const int n = w * 32 + nt * 16 + mn;
    const float bv = b0[(size_t)t * 768 + n];
#pragma unroll
    for (int r = 0; r < 4; ++r)
      xw[(size_t)t * 32768 + (size_t)(rb + dr + r) * 256 + n] = acc[nt][r] + bv;
  }
}

// ---------------- matmul K-half phase (A from LDS) ----------------
template <int NW, bool DMA>
__device__ __forceinline__ void phase(f32x4 (&acc)[2], const char* arow, const char* wb,
                                      const int (&bo)[4], const char* gnext, char* lnext,
                                      const int (&off)[8], int q) {
  waitvm<NW>();
  sb();
  f16x8 a[4], b[8];
#pragma unroll
  for (int kt = 0; kt < 4; ++kt) {
    a[kt]         = *(const f16x8*)(arow + kt * 64 + q * 16);
    b[kt * 2]     = *(const f16x8*)(wb + bo[kt]);
    b[kt * 2 + 1] = *(const f16x8*)(wb + bo[kt] + 4096);
  }
  sb();
  waitlgkm0();
  if (DMA) {
#pragma unroll
    for (int d = 0; d < 8; ++d) dma16(gnext + off[d], lnext + d * 1024);
  }
  sb();
#pragma unroll
  for (int kt = 0; kt < 4; ++kt) {
    acc[0] = __builtin_amdgcn_mfma_f32_16x16x32_f16(a[kt], b[kt * 2],     acc[0], 0, 0, 0);
    acc[1] = __builtin_amdgcn_mfma_f32_16x16x32_f16(a[kt], b[kt * 2 + 1], acc[1], 0, 0, 0);
  }
}

// ---------------- matmul K-half phase (A from registers) ----------------
template <int NW>
__device__ __forceinline__ void phaseRA(f32x4 (&acc)[2], const f16x8* af, const char* wb,
                                        const int (&bo)[4], const char* gnext, char* lnext,
                                        const int (&off)[8]) {
  waitvm<NW>();
  sb();
  f16x8 b[8];
#pragma unroll
  for (int kt = 0; kt < 4; ++kt) {
    b[kt * 2]     = *(const f16x8*)(wb + bo[kt]);
    b[kt * 2 + 1] = *(const f16x8*)(wb + bo[kt] + 4096);
  }
  sb();
  waitlgkm0();
#pragma unroll
  for (int d = 0; d < 8; ++d) dma16(gnext + off[d], lnext + d * 1024);
  sb();
#pragma unroll
  for (int kt = 0; kt < 4; ++kt) {
    acc[0] = __builtin_amdgcn_mfma_f32_16x16x32_f16(af[kt], b[kt * 2],     acc[0], 0, 0, 0);
    acc[1] = __builtin_amdgcn_mfma_f32_16x16x32_f16(af[kt], b[kt * 2 + 1], acc[1], 0, 0, 0);
  }
}

// ---------------- recurrent kernel: grid 32, 16 active (8 L0 + 8 L1) -------
// blockIdx%8 = XCD (HW round-robin). L0 WGs -> XCDs {0,1} (4 CUs each),
// L1 WGs -> XCDs {4,5}. Same-XCD WGs stream identical weights -> shared L2.
__global__ __launch_bounds__(512, 1) void rnn_kernel(
    const float* __restrict__ hidden,
    const f16* __restrict__ Wh0T, const float* __restrict__ b0,
    const f16* __restrict__ Win1T, const f16* __restrict__ Wh1T, const float* __restrict__ b1,
    const float* __restrict__ xw, f16* __restrict__ hseq, int* __restrict__ flags,
    float* __restrict__ out) {
  __shared__ __align__(16) char smem[147968];
  char* wlds = smem;                 // 8 waves x 16 KB
  char* abuf = smem + 131072;        // recurrent h (hbuf0 for L0 / hbuf1 for L1)
  char* nbuf = smem + 139520;

  // ---- XCD-aware role/group mapping ----
  const int xcd = blockIdx.x & 7, slot = blockIdx.x >> 3;   // bid%8 -> XCD
  bool isL0; int g;
  if (xcd < 2)                  { isL0 = true;  g = xcd * 4 + slot; }        // XCD 0,1
  else if (xcd >= 4 && xcd < 6) { isL0 = false; g = (xcd - 4) * 4 + slot; }  // XCD 4,5
  else return;

  const int tid = threadIdx.x;
  const int lane = tid & 63;
  const int w = tid >> 6;
  const int q = lane >> 4;
  const int mn = lane & 15;
  const int rb = g << 4;
  const int nc = w * 32 + mn;
  const int dr = q * 4;
  const int wslice = w * 16384;

  int off[8], bo[4];
#pragma unroll
  for (int d = 0; d < 8; ++d) {
    const int row = 4 * d + q;
    off[d] = row * 512 + ((mn ^ (row & 15)) << 4);
  }
#pragma unroll
  for (int kt = 0; kt < 4; ++kt)
    bo[kt] = mn * 256 + (((kt * 4 + q) ^ mn) << 4);

  // init recurrent state (layer-appropriate half of hidden)
  const float* hsrc = hidden + (isL0 ? 0 : 32768) + (size_t)rb * 256;
  for (int i = tid; i < 16 * 256; i += 512) {
    const int m = i >> 8, n = i & 255;
    *(f16*)(abuf + m * 528 + n * 2) = (f16)hsrc[m * 256 + n];
  }

  char* bufA = wlds + wslice;
  char* bufB = bufA + 8192;
  const f32x4 zero4 = {0.f, 0.f, 0.f, 0.f};
  float n0v[2][4], n1v[2][4];

  if (isL0) {
    // =================== LAYER-0 PRODUCER ===================
    const char* WB = (const char*)Wh0T;   // [t][3][256][256] f16 (transposed)
    { // prelude: DMA Wh0[0](t=0) halves
      const char* gw = WB + wslice;
#pragma unroll
      for (int d = 0; d < 8; ++d) dma16(gw + off[d], bufA + d * 1024);
#pragma unroll
      for (int d = 0; d < 8; ++d) dma16(gw + 256 + off[d], bufB + d * 1024);
      sb();
    }
    barx();

#pragma unroll 1
    for (int t = 0; t < Tt; ++t) {
      const int tn = (t < Tt - 1) ? t + 1 : t;
      const bool last = (t == Tt - 1);
      const char* wt  = WB + (size_t)t * 393216 + wslice;
      const char* wtn = WB + (size_t)tn * 393216 + wslice;

      // loop top: xw(t) [8 loads] + bias [4 loads]
      float xwv[2][4];
#pragma unroll
      for (int nt = 0; nt < 2; ++nt)
#pragma unroll
        for (int r = 0; r < 4; ++r)
          xwv[nt][r] = xw[(size_t)t * 32768 + (size_t)(rb + dr + r) * 256 + nc + nt * 16];
      const float bv1a = b0[(size_t)t * 768 + 256 + nc], bv1b = b0[(size_t)t * 768 + 256 + nc + 16];
      const float bv2a = b0[(size_t)t * 768 + 512 + nc], bv2b = b0[(size_t)t * 768 + 512 + nc + 16];
      sb();

      f32x4 acc[2];
      // ---- m0: n0 = tanh(h0@Wh0[0] + xw) ; prefetch Wh0[1]
      acc[0] = zero4; acc[1] = zero4;
      phase<20, true>(acc, abuf + mn * 528,       bufA, bo, wt + 131072,       bufA, off, q);
      phase<20, true>(acc, abuf + mn * 528 + 256, bufB, bo, wt + 131072 + 256, bufB, off, q);
      waitvm<20>();   // xw landed (leaves bias4 + Wh0[1] dmas)
      sb();
#pragma unroll
      for (int nt = 0; nt < 2; ++nt)
#pragma unroll
        for (int r = 0; r < 4; ++r) {
          float v = tanh_fast(acc[nt][r] + xwv[nt][r]);
          n0v[nt][r] = v;
          *(f16*)(nbuf + (dr + r) * 528 + (nc + nt * 16) * 2) = (f16)v;
        }
      barx();  // (1) n0 visible

      // ---- m1: n1 = relu(n0@Wh0[1] + b0[1]) + n0 ; prefetch Wh0[2]
      acc[0] = zero4; acc[1] = zero4;
      phase<8, true>(acc, nbuf + mn * 528,       bufA, bo, wt + 262144,       bufA, off, q);
      phase<8, true>(acc, nbuf + mn * 528 + 256, bufB, bo, wt + 262144 + 256, bufB, off, q);
      barx();  // (2) n0 reads done (WAR)
#pragma unroll
      for (int nt = 0; nt < 2; ++nt) {
        const float bv = nt ? bv1b : bv1a;
#pragma unroll
        for (int r = 0; r < 4; ++r) {
          float v = fmaxf(acc[nt][r] + bv, 0.f) + n0v[nt][r];
          n1v[nt][r] = v;
          *(f16*)(nbuf + (dr + r) * 528 + (nc + nt * 16) * 2) = (f16)v;
        }
      }
      barx();  // (3) n1 visible

      // ---- m2: n2 = sigmoid(n1@Wh0[2] + b0[2]) + n0 ; h0' = 0.5(n1+n2); no DMA
      acc[0] = zero4; acc[1] = zero4;
      phase<8, false>(acc, nbuf + mn * 528,       bufA, bo, wt, bufA, off, q);
      phase<0, false>(acc, nbuf + mn * 528 + 256, bufB, bo, wt, bufB, off, q);
      // epi: write h0' to abuf (LDS) + hseq (global), publish flag
#pragma unroll
      for (int nt = 0; nt < 2; ++nt) {
        const float bv = nt ? bv2b : bv2a;
#pragma unroll
        for (int r = 0; r < 4; ++r) {
          float s = sigmoid_fast(acc[nt][r] + bv);
          float hv = 0.5f * (n1v[nt][r] + s + n0v[nt][r]);
          f16 h16 = (f16)hv;
          *(f16*)(abuf + (dr + r) * 528 + (nc + nt * 16) * 2) = h16;
          hseq[((size_t)(g * 64 + t)) * 4096 + (dr + r) * 256 + nc + nt * 16] = h16;
          if (last) out[2097152 + (size_t)(rb + dr + r) * 256 + nc + nt * 16] = hv;
        }
      }
      waitvm<0>();          // all hseq stores of this wave complete
      __threadfence();      // device-scope release of data
      __syncthreads();      // all waves' stores complete
      if (tid == 0) {
        __hip_atomic_store(&flags[g * 64 + t], FLAG_MAGIC | (t + 1),
                           __ATOMIC_RELEASE, __HIP_MEMORY_SCOPE_AGENT);
      }
      sb();
      // prefetch next step's Wh0[0] halves
      {
        const char* gw = wtn;
#pragma unroll
        for (int d = 0; d < 8; ++d) dma16(gw + off[d], bufA + d * 1024);
#pragma unroll
        for (int d = 0; d < 8; ++d) dma16(gw + 256 + off[d], bufB + d * 1024);
        sb();
      }
    }
  } else {
    // =================== LAYER-1 CONSUMER ===================
    const char* WI = (const char*)Win1T;  // [t][256][256]
    const char* WH = (const char*)Wh1T;   // [t][3][256][256]
    const f16* hsg = hseq + (size_t)g * 64 * 4096;
    { // prelude: DMA Wh1[0](t=0) halves
      const char* gw = WH + wslice;
#pragma unroll
      for (int d = 0; d < 8; ++d) dma16(gw + off[d], bufA + d * 1024);
#pragma unroll
      for (int d = 0; d < 8; ++d) dma16(gw + 256 + off[d], bufB + d * 1024);
      sb();
    }
    barx();

#pragma unroll 1
    for (int t = 0; t < Tt; ++t) {
      const int tn = (t < Tt - 1) ? t + 1 : t;
      const bool last = (t == Tt - 1);
      const char* wit = WI + (size_t)t * 131072 + wslice;
      const char* wht = WH + (size_t)t * 393216 + wslice;
      const char* whn = WH + (size_t)tn * 393216 + wslice;

      // poll producer flag (acquire; drains vmcnt implicitly)
      {
        const int want = FLAG_MAGIC | (t + 1);
        while (__hip_atomic_load(&flags[g * 64 + t], __ATOMIC_ACQUIRE,
                                 __HIP_MEMORY_SCOPE_AGENT) != want) {}
      }
      sb();
      // A-fragments of h0'(t) straight from global [8 dwordx4] + biases [6]
      const char* ht = (const char*)(hsg + (size_t)t * 4096);
      f16x8 af[8];
#pragma unroll
      for (int kt = 0; kt < 8; ++kt)
        af[kt] = *(const f16x8*)(ht + mn * 512 + kt * 64 + q * 16);
      const float bv0a = b1[(size_t)t * 768 + nc],       bv0b = b1[(size_t)t * 768 + nc + 16];
      const float bv1a = b1[(size_t)t * 768 + 256 + nc], bv1b = b1[(size_t)t * 768 + 256 + nc + 16];
      const float bv2a = b1[(size_t)t * 768 + 512 + nc], bv2b = b1[(size_t)t * 768 + 512 + nc + 16];
      sb();

      f32x4 acc[2];
      acc[0] = zero4; acc[1] = zero4;
      // ---- m4 first (hides handoff): h1@Wh1[0] ; prefetch Win1
      phase<63, true>(acc, abuf + mn * 528,       bufA, bo, wit,       bufA, off, q);
      phase<63, true>(acc, abuf + mn * 528 + 256, bufB, bo, wit + 256, bufB, off, q);
      // ---- m3: h0'@Win1 (A from regs) ; prefetch Wh1[1]
      phaseRA<8>(acc, af,     bufA, bo, wht + 131072,       bufA, off);
      phaseRA<8>(acc, af + 4, bufB, bo, wht + 131072 + 256, bufB, off);
#pragma unroll
      for (int nt = 0; nt < 2; ++nt) {
        const float bv = nt ? bv0b : bv0a;
#pragma unroll
        for (int r = 0; r < 4; ++r) {
          float v = tanh_fast(acc[nt][r] + bv);
          n0v[nt][r] = v;
          *(f16*)(nbuf + (dr + r) * 528 + (nc + nt * 16) * 2) = (f16)v;
        }
      }
      barx();  // (1) n0' visible

      // ---- m5: n1' = relu(n0'@Wh1[1] + b1[1]) + n0' ; prefetch Wh1[2]
      acc[0] = zero4; acc[1] = zero4;
      phase<8, true>(acc, nbuf + mn * 528,       bufA, bo, wht + 262144,       bufA, off, q);
      phase<8, true>(acc, nbuf + mn * 528 + 256, bufB, bo, wht + 262144 + 256, bufB, off, q);
      barx();  // (2) n0' reads done (WAR)
#pragma unroll
      for (int nt = 0; nt < 2; ++nt) {
        const float bv = nt ? bv1b : bv1a;
#pragma unroll
        for (int r = 0; r < 4; ++r) {
          float v = fmaxf(acc[nt][r] + bv, 0.f) + n0v[nt][r];
          n1v[nt][r] = v;
          *(f16*)(nbuf + (dr + r) * 528 + (nc + nt * 16) * 2) = (f16)v;
        }
      }
      barx();  // (3) n1' visible

      // ---- m6: n2' = sigmoid(n1'@Wh1[2] + b1[2]) + n0' ; h1' = 0.5(n1'+n2');
      //          prefetch next step's Wh1[0]
      acc[0] = zero4; acc[1] = zero4;
      phase<8, true>(acc, nbuf + mn * 528,       bufA, bo, whn,       bufA, off, q);
      phase<8, true>(acc, nbuf + mn * 528 + 256, bufB, bo, whn + 256, bufB, off, q);
#pragma unroll
      for (int nt = 0; nt < 2; ++nt) {
        const float bv = nt ? bv2b : bv2a;
#pragma unroll
        for (int r = 0; r < 4; ++r) {
          float s = sigmoid_fast(acc[nt][r] + bv);
          float hv = 0.5f * (n1v[nt][r] + s + n0v[nt][r]);
          *(f16*)(abuf + (dr + r) * 528 + (nc + nt * 16) * 2) = (f16)hv;
          out[((size_t)(rb + dr + r) * Tt + t) * 256 + nc + nt * 16] = hv;
          if (last) out[2097152 + 32768 + (size_t)(rb + dr + r) * 256 + nc + nt * 16] = hv;
        }
      }
      barx();  // (4) step end: h1' visible, nbuf reads done
    }
  }
}

// ---------------- launch ----------------
extern "C" void kernel_launch(void* const* d_in, const int* in_sizes, int n_in,
                              void* d_out, int out_size, void* d_ws, size_t ws_size,
                              hipStream_t stream) {
  (void)in_sizes; (void)n_in; (void)out_size; (void)ws_size;
  const float* x      = (const float*)d_in[0];
  const float* hidden = (const float*)d_in[1];
  const float* Win0   = (const float*)d_in[2];
  const float* Wh0    = (const float*)d_in[3];
  const float* b0     = (const float*)d_in[4];
  const float* Win1   = (const float*)d_in[5];
  const float* Wh1    = (const float*)d_in[6];
  const float* b1     = (const float*)d_in[7];
  float* out = (float*)d_out;

  char* ws = (char*)d_ws;
  f16* Wh0T  = (f16*)(ws + WS_WH0T);
  f16* Win1T = (f16*)(ws + WS_WIN1T);
  f16* Wh1T  = (f16*)(ws + WS_WH1T);
  f16* Win0T = (f16*)(ws + WS_WIN0T);
  float* xwp = (float*)(ws + WS_XW);
  f16* hseq  = (f16*)(ws + WS_HSEQ);
  int* flags = (int*)(ws + WS_FLAGS);

  transpose_cvt_kernel<<<dim3(4096), dim3(256), 0, stream>>>(
      Wh0, Win1, Wh1, Win0, Wh0T, Win1T, Wh1T, Win0T);
  xw_kernel<<<dim3(512), dim3(512), 0, stream>>>(x, Win0T, b0, xwp);
  rnn_kernel<<<dim3(32), dim3(512), 0, stream>>>(
      hidden, Wh0T, b0, Win1T, Wh1T, b1, xwp, hseq, flags, out);
}